// Round 1
// baseline (542.023 us; speedup 1.0000x reference)
//
#include <hip/hip_runtime.h>
#include <hip/hip_bf16.h>

// MoE SwiGLU: H=2048, I=1408, E=8, TOPK=2, T=4096 tokens (8192 pairs).
// Grouped-GEMM approach: deterministic binning -> gemm1(+SwiGLU fused) -> gemm2(+weighted scatter).

typedef __bf16 bf16;
typedef bf16 bf16x8 __attribute__((ext_vector_type(8)));
typedef float f32x4 __attribute__((ext_vector_type(4)));

constexpr int Hdim = 2048;
constexpr int Idim = 1408;
constexpr int NE = 8;
constexpr int TOPK = 2;
constexpr int NPAIR = 8192;   // T * TOPK
constexpr int BM = 128;
constexpr int BK = 64;

// ---------------- binning (deterministic) ----------------

__global__ void k_bin1(const int* __restrict__ eidx, int* __restrict__ chunkhist) {
    __shared__ int h[NE];
    int t = threadIdx.x;
    if (t < NE) h[t] = 0;
    __syncthreads();
    int p = blockIdx.x * 256 + t;
    atomicAdd(&h[eidx[p]], 1);
    __syncthreads();
    if (t < NE) chunkhist[blockIdx.x * NE + t] = h[t];
}

__global__ void k_bin2(int* __restrict__ meta, const int* __restrict__ chunkhist,
                       int* __restrict__ chunkbase) {
    if (threadIdx.x == 0) {
        int counts[NE];
        for (int e = 0; e < NE; e++) counts[e] = 0;
        for (int b = 0; b < 32; b++)
            for (int e = 0; e < NE; e++) {
                chunkbase[b * NE + e] = counts[e];
                counts[e] += chunkhist[b * NE + e];
            }
        int acc = 0;
        for (int e = 0; e < NE; e++) {
            meta[e] = counts[e];      // counts
            meta[8 + e] = acc;        // exclusive offsets
            acc += counts[e];
        }
    }
}

__global__ void k_bin3(const int* __restrict__ eidx, const float* __restrict__ wts,
                       const int* __restrict__ meta, const int* __restrict__ chunkbase,
                       int* __restrict__ token_id, float* __restrict__ weightv) {
    __shared__ int earr[256];
    int t = threadIdx.x;
    int p = blockIdx.x * 256 + t;
    int e = eidx[p];
    earr[t] = e;
    __syncthreads();
    int rank = 0;
    for (int q = 0; q < t; q++) rank += (earr[q] == e) ? 1 : 0;
    int pos = meta[8 + e] + chunkbase[blockIdx.x * NE + e] + rank;
    token_id[pos] = p / TOPK;
    weightv[pos] = wts[p];
}

// ---------------- GEMM1: gu = X_e * w13[e]^T, fused SwiGLU ----------------
// grid: x = 11 (gate col tile, up tile = +11), y = 64 (m tiles, early exit), z = 8 (expert)

__global__ __launch_bounds__(256, 2) void k_gemm1(
    const float* __restrict__ x, const float* __restrict__ w13,
    const int* __restrict__ meta, bf16* __restrict__ hact) {
    const int e = blockIdx.z;
    const int n_e = meta[e];
    const int m0 = blockIdx.y * BM;
    if (m0 >= n_e) return;
    const int base = meta[8 + e];
    const int* toks = meta + 64 + base;
    const float* wgat = w13 + (size_t)e * (2 * Idim) * Hdim + (size_t)(blockIdx.x * 128) * Hdim;
    const float* wup = wgat + (size_t)Idim * Hdim;

    __shared__ bf16 As[BM * BK];
    __shared__ bf16 Bg[128 * BK];
    __shared__ bf16 Bu[128 * BK];

    const int tid = threadIdx.x;
    const int lane = tid & 63;
    const int wid = tid >> 6;
    const int wr = wid >> 1, wc = wid & 1;
    const int l16 = lane & 15, lq = lane >> 4;

    // staging descriptors: 4 slots (16B LDS chunks) per thread per matrix
    const float* pa[4];
    const float* pg[4];
    const float* pu[4];
    int lo[4];
#pragma unroll
    for (int s = 0; s < 4; ++s) {
        int sid = tid + s * 256;
        int row = sid >> 3, sl = sid & 7;
        lo[s] = row * BK + ((sl ^ (row & 7)) * 8);   // XOR swizzle (16B granules)
        int r = m0 + row;
        if (r >= n_e) r = n_e - 1;                    // clamp: keeps reads in-bounds
        pa[s] = x + (size_t)toks[r] * Hdim + sl * 8;
        pg[s] = wgat + (size_t)row * Hdim + sl * 8;
        pu[s] = wup + (size_t)row * Hdim + sl * 8;
    }

    f32x4 accg[4][4], accu[4][4];
#pragma unroll
    for (int m = 0; m < 4; m++)
#pragma unroll
        for (int n = 0; n < 4; n++) {
            accg[m][n] = f32x4{0.f, 0.f, 0.f, 0.f};
            accu[m][n] = f32x4{0.f, 0.f, 0.f, 0.f};
        }

    for (int k0 = 0; k0 < Hdim; k0 += BK) {
        __syncthreads();
#pragma unroll
        for (int s = 0; s < 4; ++s) {
            f32x4 a0 = *reinterpret_cast<const f32x4*>(pa[s] + k0);
            f32x4 a1 = *reinterpret_cast<const f32x4*>(pa[s] + k0 + 4);
            f32x4 g0 = *reinterpret_cast<const f32x4*>(pg[s] + k0);
            f32x4 g1 = *reinterpret_cast<const f32x4*>(pg[s] + k0 + 4);
            f32x4 u0 = *reinterpret_cast<const f32x4*>(pu[s] + k0);
            f32x4 u1 = *reinterpret_cast<const f32x4*>(pu[s] + k0 + 4);
            bf16x8 av, gv, uv;
#pragma unroll
            for (int j = 0; j < 4; j++) {
                av[j] = (bf16)a0[j]; av[4 + j] = (bf16)a1[j];
                gv[j] = (bf16)g0[j]; gv[4 + j] = (bf16)g1[j];
                uv[j] = (bf16)u0[j]; uv[4 + j] = (bf16)u1[j];
            }
            *reinterpret_cast<bf16x8*>(&As[lo[s]]) = av;
            *reinterpret_cast<bf16x8*>(&Bg[lo[s]]) = gv;
            *reinterpret_cast<bf16x8*>(&Bu[lo[s]]) = uv;
        }
        __syncthreads();
#pragma unroll
        for (int kk = 0; kk < 2; ++kk) {
            bf16x8 af[4], bgf[4], buf_[4];
#pragma unroll
            for (int m = 0; m < 4; m++) {
                int row = wr * 64 + m * 16 + l16;
                int sl = ((kk * 4 + lq) ^ (l16 & 7)) * 8;
                af[m] = *reinterpret_cast<const bf16x8*>(&As[row * BK + sl]);
            }
#pragma unroll
            for (int n = 0; n < 4; n++) {
                int row = wc * 64 + n * 16 + l16;
                int sl = ((kk * 4 + lq) ^ (l16 & 7)) * 8;
                bgf[n] = *reinterpret_cast<const bf16x8*>(&Bg[row * BK + sl]);
                buf_[n] = *reinterpret_cast<const bf16x8*>(&Bu[row * BK + sl]);
            }
#pragma unroll
            for (int m = 0; m < 4; m++)
#pragma unroll
                for (int n = 0; n < 4; n++) {
                    accg[m][n] = __builtin_amdgcn_mfma_f32_16x16x32_bf16(af[m], bgf[n], accg[m][n], 0, 0, 0);
                    accu[m][n] = __builtin_amdgcn_mfma_f32_16x16x32_bf16(af[m], buf_[n], accu[m][n], 0, 0, 0);
                }
        }
    }

    // epilogue: silu(g)*u -> hact (bf16), C layout: col=lane&15, row=(lane>>4)*4+reg
    const int colbase = blockIdx.x * 128 + wc * 64;
#pragma unroll
    for (int m = 0; m < 4; m++) {
        int lr0 = m0 + wr * 64 + m * 16 + lq * 4;
#pragma unroll
        for (int j = 0; j < 4; j++) {
            int lr = lr0 + j;
            if (lr < n_e) {
                size_t rowoff = (size_t)(base + lr) * Idim;
#pragma unroll
                for (int n = 0; n < 4; n++) {
                    float g = accg[m][n][j], u = accu[m][n][j];
                    float v = (g / (1.f + __expf(-g))) * u;
                    hact[rowoff + colbase + n * 16 + l16] = (bf16)v;
                }
            }
        }
    }
}

// ---------------- GEMM2: y = hact * down_proj[e]^T, weighted scatter-add ----------------
// grid: x = 16 (H col tiles), y = 64 (m tiles, early exit), z = 8 (expert)

__global__ __launch_bounds__(256, 2) void k_gemm2(
    const bf16* __restrict__ hact, const float* __restrict__ dproj,
    const int* __restrict__ meta, const float* __restrict__ weightv,
    float* __restrict__ out) {
    const int e = blockIdx.z;
    const int n_e = meta[e];
    const int m0 = blockIdx.y * BM;
    if (m0 >= n_e) return;
    const int base = meta[8 + e];
    const int* toks = meta + 64 + base;
    const float* wb = dproj + (size_t)e * Hdim * Idim + (size_t)(blockIdx.x * 128) * Idim;

    __shared__ bf16 As[BM * BK];
    __shared__ bf16 Bs[128 * BK];

    const int tid = threadIdx.x;
    const int lane = tid & 63;
    const int wid = tid >> 6;
    const int wr = wid >> 1, wc = wid & 1;
    const int l16 = lane & 15, lq = lane >> 4;

    const bf16* pa[4];
    const float* pb[4];
    int lo[4];
#pragma unroll
    for (int s = 0; s < 4; ++s) {
        int sid = tid + s * 256;
        int row = sid >> 3, sl = sid & 7;
        lo[s] = row * BK + ((sl ^ (row & 7)) * 8);
        int r = m0 + row;
        if (r >= n_e) r = n_e - 1;
        pa[s] = hact + (size_t)(base + r) * Idim + sl * 8;
        pb[s] = wb + (size_t)row * Idim + sl * 8;
    }

    f32x4 acc[4][4];
#pragma unroll
    for (int m = 0; m < 4; m++)
#pragma unroll
        for (int n = 0; n < 4; n++) acc[m][n] = f32x4{0.f, 0.f, 0.f, 0.f};

    for (int k0 = 0; k0 < Idim; k0 += BK) {
        __syncthreads();
#pragma unroll
        for (int s = 0; s < 4; ++s) {
            bf16x8 av = *reinterpret_cast<const bf16x8*>(pa[s] + k0);
            f32x4 b0 = *reinterpret_cast<const f32x4*>(pb[s] + k0);
            f32x4 b1 = *reinterpret_cast<const f32x4*>(pb[s] + k0 + 4);
            bf16x8 bv;
#pragma unroll
            for (int j = 0; j < 4; j++) { bv[j] = (bf16)b0[j]; bv[4 + j] = (bf16)b1[j]; }
            *reinterpret_cast<bf16x8*>(&As[lo[s]]) = av;
            *reinterpret_cast<bf16x8*>(&Bs[lo[s]]) = bv;
        }
        __syncthreads();
#pragma unroll
        for (int kk = 0; kk < 2; ++kk) {
            bf16x8 af[4], bf_[4];
#pragma unroll
            for (int m = 0; m < 4; m++) {
                int row = wr * 64 + m * 16 + l16;
                int sl = ((kk * 4 + lq) ^ (l16 & 7)) * 8;
                af[m] = *reinterpret_cast<const bf16x8*>(&As[row * BK + sl]);
            }
#pragma unroll
            for (int n = 0; n < 4; n++) {
                int row = wc * 64 + n * 16 + l16;
                int sl = ((kk * 4 + lq) ^ (l16 & 7)) * 8;
                bf_[n] = *reinterpret_cast<const bf16x8*>(&Bs[row * BK + sl]);
            }
#pragma unroll
            for (int m = 0; m < 4; m++)
#pragma unroll
                for (int n = 0; n < 4; n++)
                    acc[m][n] = __builtin_amdgcn_mfma_f32_16x16x32_bf16(af[m], bf_[n], acc[m][n], 0, 0, 0);
        }
    }

    const int colbase = blockIdx.x * 128 + wc * 64;
#pragma unroll
    for (int m = 0; m < 4; m++) {
        int lr0 = m0 + wr * 64 + m * 16 + lq * 4;
#pragma unroll
        for (int j = 0; j < 4; j++) {
            int lr = lr0 + j;
            if (lr < n_e) {
                int tok = toks[lr];
                float w = weightv[base + lr];
#pragma unroll
                for (int n = 0; n < 4; n++) {
                    float v = acc[m][n][j] * w;
                    unsafeAtomicAdd(&out[(size_t)tok * Hdim + colbase + n * 16 + l16], v);
                }
            }
        }
    }
}

// ---------------- launch ----------------

extern "C" void kernel_launch(void* const* d_in, const int* in_sizes, int n_in,
                              void* d_out, int out_size, void* d_ws, size_t ws_size,
                              hipStream_t stream) {
    const float* x = (const float*)d_in[0];
    const int* eidx = (const int*)d_in[1];
    const float* ewts = (const float*)d_in[2];
    const float* w13 = (const float*)d_in[3];
    const float* dproj = (const float*)d_in[4];
    float* out = (float*)d_out;

    // ws layout
    int* meta = (int*)d_ws;                    // [0..7] counts, [8..15] offsets, pad to 64
    int* token_id = meta + 64;                 // [NPAIR]
    float* weightv = (float*)(token_id + NPAIR);  // [NPAIR]
    int* chunkhist = (int*)(weightv + NPAIR);  // [32*NE]
    int* chunkbase = chunkhist + 256;          // [32*NE]
    bf16* hact = (bf16*)(chunkbase + 256);     // [NPAIR][Idim] bf16, 16B-aligned

    hipMemsetAsync(d_out, 0, (size_t)out_size * sizeof(float), stream);

    k_bin1<<<32, 256, 0, stream>>>(eidx, chunkhist);
    k_bin2<<<1, 64, 0, stream>>>(meta, chunkhist, chunkbase);
    k_bin3<<<32, 256, 0, stream>>>(eidx, ewts, meta, chunkbase, token_id, weightv);

    k_gemm1<<<dim3(11, 64, 8), 256, 0, stream>>>(x, w13, meta, hact);
    k_gemm2<<<dim3(16, 64, 8), 256, 0, stream>>>(hact, dproj, meta, weightv, out);
}